// Round 1
// baseline (1517.661 us; speedup 1.0000x reference)
//
#include <hip/hip_runtime.h>
#include <cfloat>
#include <cmath>

#define NPTS 131072
#define NC   512
#define NDIM 3

// ws layout (float indices):
//  [0, NPTS)            z_n  (per-point logsumexp over components)
//  [NPTS, +512)         S_c  (sum of gamma per component)
//  [+512, +2048)        T_c  (sum of gamma*x per component, [c][3])
//  [+2048, +3584)       mu_new [c][3]
//  [+3584, +4096)       A_c = |mu_new|^2 * inv2s2n - logpi_c
//  [+4096..]            misc: [0]=sum(gamma*D2), [1]=inv2s2n, [2]=d*log(sigma_new)
#define S_OFF     (NPTS)
#define T_OFF     (NPTS + NC)
#define MUNEW_OFF (NPTS + NC + NC * 3)
#define A_OFF     (MUNEW_OFF + NC * 3)
#define MISC_OFF  (A_OFF + NC)

__device__ __forceinline__ float waveSum(float v) {
#pragma unroll
  for (int off = 32; off > 0; off >>= 1) v += __shfl_down(v, off, 64);
  return v;
}
__device__ __forceinline__ float waveMax(float v) {
#pragma unroll
  for (int off = 32; off > 0; off >>= 1) v = fmaxf(v, __shfl_down(v, off, 64));
  return v;
}

// ---------------------------------------------------------------------------
// Pass 1: per-point E-step. Computes z_n = lse_c(logit), accumulates
// S_c = sum_n gamma, T_c = sum_n gamma*x, and sum(gamma*D2) for sigma_new.
// ---------------------------------------------------------------------------
__global__ __launch_bounds__(256) void k_estep(
    const float* __restrict__ X, const float* __restrict__ mu,
    const float* __restrict__ w, const float* __restrict__ sigma,
    float* __restrict__ ws) {
  __shared__ float s_mu[NC * 3];
  __shared__ float s_w[NC];
  __shared__ float s_S[NC];
  __shared__ float s_T[NC * 3];
  __shared__ float s_red[4];

  const int t = threadIdx.x;
  for (int i = t; i < NC * 3; i += 256) { s_mu[i] = mu[i]; s_T[i] = 0.f; }
  for (int i = t; i < NC; i += 256)     { s_w[i]  = w[i];  s_S[i] = 0.f; }
  __syncthreads();

  const int n = blockIdx.x * 256 + t;
  const float x0 = X[3 * n], x1 = X[3 * n + 1], x2 = X[3 * n + 2];
  const float sg = sigma[0];
  const float inv2s2 = 1.0f / (2.0f * sg * sg);

  // phase 1: max logit over components
  float m = -FLT_MAX;
#pragma unroll 4
  for (int c = 0; c < NC; ++c) {
    float d0 = x0 - s_mu[3 * c], d1 = x1 - s_mu[3 * c + 1], d2 = x2 - s_mu[3 * c + 2];
    float q = d0 * d0 + d1 * d1 + d2 * d2;
    float lg = fmaf(-q, inv2s2, s_w[c]);
    m = fmaxf(m, lg);
  }
  // phase 2: sum exp -> z
  float ssum = 0.f;
#pragma unroll 4
  for (int c = 0; c < NC; ++c) {
    float d0 = x0 - s_mu[3 * c], d1 = x1 - s_mu[3 * c + 1], d2 = x2 - s_mu[3 * c + 2];
    float q = d0 * d0 + d1 * d1 + d2 * d2;
    float lg = fmaf(-q, inv2s2, s_w[c]);
    ssum += __expf(lg - m);
  }
  const float z = m + __logf(ssum);
  ws[n] = z;

  // phase 3: accumulate S, T via lane-staggered LDS atomics; gd locally
  float gd = 0.f;
  for (int i = 0; i < NC; ++i) {
    int c = (i + t) & (NC - 1);
    float d0 = x0 - s_mu[3 * c], d1 = x1 - s_mu[3 * c + 1], d2 = x2 - s_mu[3 * c + 2];
    float q = d0 * d0 + d1 * d1 + d2 * d2;
    float lg = fmaf(-q, inv2s2, s_w[c]);
    float g = __expf(lg - z);
    atomicAdd(&s_S[c], g);
    atomicAdd(&s_T[3 * c], g * x0);
    atomicAdd(&s_T[3 * c + 1], g * x1);
    atomicAdd(&s_T[3 * c + 2], g * x2);
    gd = fmaf(g, q, gd);
  }

  float r = waveSum(gd);
  if ((t & 63) == 0) s_red[t >> 6] = r;
  __syncthreads();  // also guarantees all LDS atomics above are done
  if (t == 0) atomicAdd(&ws[MISC_OFF], s_red[0] + s_red[1] + s_red[2] + s_red[3]);
  for (int i = t; i < NC; i += 256)     atomicAdd(&ws[S_OFF + i], s_S[i]);
  for (int i = t; i < NC * 3; i += 256) atomicAdd(&ws[T_OFF + i], s_T[i]);
}

// ---------------------------------------------------------------------------
// Pass 2: M-step scalars. One block, 512 threads (one per component).
// logpi_c = h_c - lse(h)   (the mean-subtraction in the reference cancels).
// ---------------------------------------------------------------------------
__global__ __launch_bounds__(512) void k_mstep(float* __restrict__ ws,
                                               float* __restrict__ out) {
  __shared__ float s_red[8];
  __shared__ float s_bc[2];
  const int t = threadIdx.x;  // 0..511 = component id

  float S = ws[S_OFF + t];
  float Sc = fmaxf(S, 1e-30f);
  float h = __logf(Sc);
  float m0 = ws[T_OFF + 3 * t] / Sc;
  float m1 = ws[T_OFF + 3 * t + 1] / Sc;
  float m2 = ws[T_OFF + 3 * t + 2] / Sc;
  ws[MUNEW_OFF + 3 * t] = m0;
  ws[MUNEW_OFF + 3 * t + 1] = m1;
  ws[MUNEW_OFF + 3 * t + 2] = m2;

  // lse over 512 h values
  float hm = waveMax(h);
  if ((t & 63) == 0) s_red[t >> 6] = hm;
  __syncthreads();
  if (t == 0) {
    float v = s_red[0];
    for (int i = 1; i < 8; ++i) v = fmaxf(v, s_red[i]);
    s_bc[0] = v;
  }
  __syncthreads();
  const float hM = s_bc[0];
  float es = waveSum(__expf(h - hM));
  if ((t & 63) == 0) s_red[t >> 6] = es;
  __syncthreads();
  if (t == 0) {
    float v = 0.f;
    for (int i = 0; i < 8; ++i) v += s_red[i];
    s_bc[1] = hM + __logf(v);
  }
  __syncthreads();
  const float logpi = h - s_bc[1];

  const float gd = ws[MISC_OFF];
  const float sn2 = gd / (float)(NDIM * NPTS);
  const float inv2s2n = 1.0f / (2.0f * sn2);
  const float dlogsig = 1.5f * __logf(sn2);  // d * log(sigma_new), d=3

  ws[A_OFF + t] = (m0 * m0 + m1 * m1 + m2 * m2) * inv2s2n - logpi;
  if (t == 0) {
    ws[MISC_OFF + 1] = inv2s2n;
    ws[MISC_OFF + 2] = dlogsig;
    out[NPTS * NDIM] = 0.f;  // harness re-poisons d_out; we own the zero-init
  }
}

// ---------------------------------------------------------------------------
// Pass 3: per-point Y = gamma @ mu_new and Cfe accumulation.
// ---------------------------------------------------------------------------
__global__ __launch_bounds__(256) void k_final(
    const float* __restrict__ X, const float* __restrict__ mu,
    const float* __restrict__ w, const float* __restrict__ sigma,
    const float* __restrict__ ws, float* __restrict__ out) {
  __shared__ float s_mu[NC * 3];
  __shared__ float s_w[NC];
  __shared__ float s_mn[NC * 3];
  __shared__ float s_A[NC];
  __shared__ float s_red[4];

  const int t = threadIdx.x;
  for (int i = t; i < NC * 3; i += 256) { s_mu[i] = mu[i]; s_mn[i] = ws[MUNEW_OFF + i]; }
  for (int i = t; i < NC; i += 256)     { s_w[i] = w[i];   s_A[i] = ws[A_OFF + i]; }
  __syncthreads();

  const int n = blockIdx.x * 256 + t;
  const float x0 = X[3 * n], x1 = X[3 * n + 1], x2 = X[3 * n + 2];
  const float sg = sigma[0];
  const float inv2s2 = 1.0f / (2.0f * sg * sg);
  const float z = ws[n];
  const float inv2s2n = ws[MISC_OFF + 1];
  const float dlogsig = ws[MISC_OFF + 2];

  float y0 = 0.f, y1 = 0.f, y2 = 0.f, acc = 0.f, sumg = 0.f;
#pragma unroll 2
  for (int c = 0; c < NC; ++c) {
    float d0 = x0 - s_mu[3 * c], d1 = x1 - s_mu[3 * c + 1], d2 = x2 - s_mu[3 * c + 2];
    float q = d0 * d0 + d1 * d1 + d2 * d2;
    float lg = fmaf(-q, inv2s2, s_w[c]) - z;  // lgamma[n,c]
    float g = __expf(lg);
    sumg += g;
    y0 = fmaf(g, s_mn[3 * c], y0);
    y1 = fmaf(g, s_mn[3 * c + 1], y1);
    y2 = fmaf(g, s_mn[3 * c + 2], y2);
    acc = fmaf(g, s_A[c] + lg, acc);
  }
  const float yn2 = y0 * y0 + y1 * y1 + y2 * y2;
  const float cfe = acc + sumg * (dlogsig - yn2 * inv2s2n);

  out[3 * n] = y0;
  out[3 * n + 1] = y1;
  out[3 * n + 2] = y2;

  float r = waveSum(cfe);
  if ((t & 63) == 0) s_red[t >> 6] = r;
  __syncthreads();
  if (t == 0) atomicAdd(&out[NPTS * NDIM], s_red[0] + s_red[1] + s_red[2] + s_red[3]);
}

extern "C" void kernel_launch(void* const* d_in, const int* in_sizes, int n_in,
                              void* d_out, int out_size, void* d_ws, size_t ws_size,
                              hipStream_t stream) {
  const float* X = (const float*)d_in[0];
  const float* mu = (const float*)d_in[1];
  const float* w = (const float*)d_in[2];
  const float* sigma = (const float*)d_in[3];
  float* out = (float*)d_out;
  float* ws = (float*)d_ws;

  // zero the accumulator tail of ws (S, T, misc); z region is write-before-read
  hipMemsetAsync((char*)d_ws + (size_t)NPTS * sizeof(float), 0,
                 (size_t)4104 * sizeof(float), stream);

  k_estep<<<NPTS / 256, 256, 0, stream>>>(X, mu, w, sigma, ws);
  k_mstep<<<1, 512, 0, stream>>>(ws, out);
  k_final<<<NPTS / 256, 256, 0, stream>>>(X, mu, w, sigma, ws, out);
}

// Round 2
// 232.730 us; speedup vs baseline: 6.5211x; 6.5211x over previous
//
#include <hip/hip_runtime.h>
#include <cfloat>
#include <cmath>

#define NPTS 131072
#define NC   512
#define NDIM 3

// ws float-index layout (total 6656 floats = 26 KB):
//  PM4  [0, 2048)    : folded per-component float4 (2*mu/2s2, w - |mu|^2/2s2)
//  PQ4  [2048, 4096) : per-component float4 (mu_new[3], A_c)
//  S    [4096, 4608) : sum gamma per component
//  T    [4608, 6144) : sum gamma*x per component [c][3]
//  MISC [6144, 6152) : [0]=sum|x|^2, [1]=inv2s2_new, [2]=d*log(sigma_new)
// z_n is staged in d_out[3n] (written by k_estep, consumed then overwritten
// by the same thread of k_final).
#define PM4_OFF  0
#define PQ4_OFF  2048
#define S_OFF    4096
#define T_OFF    4608
#define MISC_OFF 6144

__device__ __forceinline__ float waveSum(float v) {
#pragma unroll
  for (int off = 32; off > 0; off >>= 1) v += __shfl_down(v, off, 64);
  return v;
}
__device__ __forceinline__ float waveMax(float v) {
#pragma unroll
  for (int off = 32; off > 0; off >>= 1) v = fmaxf(v, __shfl_down(v, off, 64));
  return v;
}

// ---------------------------------------------------------------------------
// Prep: fold sigma/mu/w into the packed pm array; zero accumulators.
// ---------------------------------------------------------------------------
__global__ __launch_bounds__(512) void k_prep(
    const float* __restrict__ mu, const float* __restrict__ w,
    const float* __restrict__ sigma, float* __restrict__ ws) {
  const int t = threadIdx.x;  // component id
  const float sg = sigma[0];
  const float inv2s2 = 1.0f / (2.0f * sg * sg);
  const float m0 = mu[3 * t], m1 = mu[3 * t + 1], m2 = mu[3 * t + 2];
  float4* pm = (float4*)(ws + PM4_OFF);
  pm[t] = make_float4(2.0f * inv2s2 * m0, 2.0f * inv2s2 * m1, 2.0f * inv2s2 * m2,
                      w[t] - (m0 * m0 + m1 * m1 + m2 * m2) * inv2s2);
  ws[S_OFF + t] = 0.f;
  ws[T_OFF + 3 * t] = 0.f;
  ws[T_OFF + 3 * t + 1] = 0.f;
  ws[T_OFF + 3 * t + 2] = 0.f;
  if (t < 8) ws[MISC_OFF + t] = 0.f;
}

// ---------------------------------------------------------------------------
// E-step: z_n = lse_c(logit'), then TRANSPOSED accumulation of S_c, T_c
// (2 components per thread, all in registers — no inner-loop atomics).
// ---------------------------------------------------------------------------
__global__ __launch_bounds__(256) void k_estep(
    const float* __restrict__ X, float* __restrict__ ws,
    float* __restrict__ out) {
  __shared__ float4 s_pt[256];
  __shared__ float s_red[4];
  const int t = threadIdx.x;
  const int n = blockIdx.x * 256 + t;
  const float4* __restrict__ pm = (const float4*)(ws + PM4_OFF);
  const float x0 = X[3 * n], x1 = X[3 * n + 1], x2 = X[3 * n + 2];

  // pass 1: max of shifted logit l'_c = x . pm.xyz + pm.w
  float m = -FLT_MAX;
#pragma unroll 8
  for (int c = 0; c < NC; ++c) {
    float4 p = pm[c];
    float l = fmaf(p.x, x0, fmaf(p.y, x1, fmaf(p.z, x2, p.w)));
    m = fmaxf(m, l);
  }
  // pass 2: logsumexp
  float ssum = 0.f;
#pragma unroll 8
  for (int c = 0; c < NC; ++c) {
    float4 p = pm[c];
    float l = fmaf(p.x, x0, fmaf(p.y, x1, fmaf(p.z, x2, p.w)));
    ssum += __expf(l - m);
  }
  const float z = m + __logf(ssum);
  out[3 * n] = z;  // staged for k_final (same thread reads then overwrites)

  s_pt[t] = make_float4(x0, x1, x2, z);
  __syncthreads();

  // transposed pass: thread t owns components t and t+256
  const float4 p1 = pm[t];
  const float4 p2 = pm[t + 256];
  float S1 = 0.f, T1x = 0.f, T1y = 0.f, T1z = 0.f;
  float S2 = 0.f, T2x = 0.f, T2y = 0.f, T2z = 0.f;
#pragma unroll 4
  for (int i = 0; i < 256; ++i) {
    float4 pt = s_pt[i];  // broadcast ds_read_b128
    float l1 = fmaf(p1.x, pt.x, fmaf(p1.y, pt.y, fmaf(p1.z, pt.z, p1.w)));
    float l2 = fmaf(p2.x, pt.x, fmaf(p2.y, pt.y, fmaf(p2.z, pt.z, p2.w)));
    float g1 = __expf(l1 - pt.w);
    float g2 = __expf(l2 - pt.w);
    S1 += g1; T1x = fmaf(g1, pt.x, T1x); T1y = fmaf(g1, pt.y, T1y); T1z = fmaf(g1, pt.z, T1z);
    S2 += g2; T2x = fmaf(g2, pt.x, T2x); T2y = fmaf(g2, pt.y, T2y); T2z = fmaf(g2, pt.z, T2z);
  }
  atomicAdd(&ws[S_OFF + t], S1);
  atomicAdd(&ws[T_OFF + 3 * t], T1x);
  atomicAdd(&ws[T_OFF + 3 * t + 1], T1y);
  atomicAdd(&ws[T_OFF + 3 * t + 2], T1z);
  atomicAdd(&ws[S_OFF + t + 256], S2);
  atomicAdd(&ws[T_OFF + 3 * (t + 256)], T2x);
  atomicAdd(&ws[T_OFF + 3 * (t + 256) + 1], T2y);
  atomicAdd(&ws[T_OFF + 3 * (t + 256) + 2], T2z);

  // sum |x|^2 (for closed-form sum(gamma*D2) in k_mstep)
  float r = waveSum(x0 * x0 + x1 * x1 + x2 * x2);
  if ((t & 63) == 0) s_red[t >> 6] = r;
  __syncthreads();
  if (t == 0) atomicAdd(&ws[MISC_OFF], s_red[0] + s_red[1] + s_red[2] + s_red[3]);
}

// ---------------------------------------------------------------------------
// M-step: one block, 512 threads (one per component).
// gd = sum(gamma*D2) = sum|x|^2 + sum_c (S_c|mu_c|^2 - 2 mu_c . T_c)
// logpi_c = h_c - lse(h)   (mean-subtraction cancels algebraically)
// ---------------------------------------------------------------------------
__global__ __launch_bounds__(512) void k_mstep(
    const float* __restrict__ mu, float* __restrict__ ws,
    float* __restrict__ out) {
  __shared__ float s_red[8];
  __shared__ float s_red2[8];
  __shared__ float s_bc[4];
  const int t = threadIdx.x;  // component id

  const float S = ws[S_OFF + t];
  const float Sc = fmaxf(S, 1e-30f);
  const float h = __logf(Sc);
  const float T0 = ws[T_OFF + 3 * t], T1 = ws[T_OFF + 3 * t + 1], T2 = ws[T_OFF + 3 * t + 2];
  const float m0 = T0 / Sc, m1 = T1 / Sc, m2 = T2 / Sc;

  const float o0 = mu[3 * t], o1 = mu[3 * t + 1], o2 = mu[3 * t + 2];
  const float gdp = S * (o0 * o0 + o1 * o1 + o2 * o2)
                    - 2.0f * (o0 * T0 + o1 * T1 + o2 * T2);

  // max of h
  float hm = waveMax(h);
  if ((t & 63) == 0) s_red[t >> 6] = hm;
  __syncthreads();
  if (t == 0) {
    float v = s_red[0];
    for (int i = 1; i < 8; ++i) v = fmaxf(v, s_red[i]);
    s_bc[0] = v;
  }
  __syncthreads();
  const float hM = s_bc[0];

  // sum exp(h - hM) and sum gdp
  float es = waveSum(__expf(h - hM));
  float gs = waveSum(gdp);
  if ((t & 63) == 0) { s_red[t >> 6] = es; s_red2[t >> 6] = gs; }
  __syncthreads();
  if (t == 0) {
    float esum = 0.f, gsum = 0.f;
    for (int i = 0; i < 8; ++i) { esum += s_red[i]; gsum += s_red2[i]; }
    s_bc[1] = hM + __logf(esum);                       // lse(h)
    const float gd = fmaxf(ws[MISC_OFF] + gsum, 1e-20f);
    const float sn2 = gd * (1.0f / (3.0f * (float)NPTS));  // sigma_new^2
    s_bc[2] = 1.0f / (2.0f * sn2);                     // inv2s2_new
    s_bc[3] = 1.5f * __logf(sn2);                      // d*log(sigma_new)
  }
  __syncthreads();

  const float logpi = h - s_bc[1];
  const float A = (m0 * m0 + m1 * m1 + m2 * m2) * s_bc[2] - logpi;
  ((float4*)(ws + PQ4_OFF))[t] = make_float4(m0, m1, m2, A);
  if (t == 0) {
    ws[MISC_OFF + 1] = s_bc[2];
    ws[MISC_OFF + 2] = s_bc[3];
    out[NPTS * NDIM] = 0.f;  // Cfe accumulator (harness re-poisons d_out)
  }
}

// ---------------------------------------------------------------------------
// Final: Y = gamma @ mu_new and Cfe. Component data via uniform-index packed
// float4 global loads (scalar cache / L1 broadcast) — no LDS in the hot loop.
// ---------------------------------------------------------------------------
__global__ __launch_bounds__(256) void k_final(
    const float* __restrict__ X, const float* __restrict__ ws,
    float* __restrict__ out) {
  __shared__ float s_red[4];
  const int t = threadIdx.x;
  const int n = blockIdx.x * 256 + t;
  const float4* __restrict__ pm = (const float4*)(ws + PM4_OFF);
  const float4* __restrict__ pq = (const float4*)(ws + PQ4_OFF);

  const float x0 = X[3 * n], x1 = X[3 * n + 1], x2 = X[3 * n + 2];
  const float z = out[3 * n];  // staged by k_estep
  const float inv2s2n = ws[MISC_OFF + 1];
  const float dlogsig = ws[MISC_OFF + 2];

  float y0 = 0.f, y1 = 0.f, y2 = 0.f, acc = 0.f, sumg = 0.f;
#pragma unroll 4
  for (int c = 0; c < NC; ++c) {
    float4 p = pm[c];
    float4 q = pq[c];
    float l = fmaf(p.x, x0, fmaf(p.y, x1, fmaf(p.z, x2, p.w))) - z;  // lgamma
    float g = __expf(l);
    sumg += g;
    y0 = fmaf(g, q.x, y0);
    y1 = fmaf(g, q.y, y1);
    y2 = fmaf(g, q.z, y2);
    acc = fmaf(g, q.w + l, acc);
  }
  const float yn2 = y0 * y0 + y1 * y1 + y2 * y2;
  const float cfe = acc + sumg * (dlogsig - yn2 * inv2s2n);

  out[3 * n] = y0;
  out[3 * n + 1] = y1;
  out[3 * n + 2] = y2;

  float r = waveSum(cfe);
  if ((t & 63) == 0) s_red[t >> 6] = r;
  __syncthreads();
  if (t == 0) atomicAdd(&out[NPTS * NDIM], s_red[0] + s_red[1] + s_red[2] + s_red[3]);
}

extern "C" void kernel_launch(void* const* d_in, const int* in_sizes, int n_in,
                              void* d_out, int out_size, void* d_ws, size_t ws_size,
                              hipStream_t stream) {
  const float* X = (const float*)d_in[0];
  const float* mu = (const float*)d_in[1];
  const float* w = (const float*)d_in[2];
  const float* sigma = (const float*)d_in[3];
  float* out = (float*)d_out;
  float* ws = (float*)d_ws;

  k_prep<<<1, 512, 0, stream>>>(mu, w, sigma, ws);
  k_estep<<<NPTS / 256, 256, 0, stream>>>(X, ws, out);
  k_mstep<<<1, 512, 0, stream>>>(mu, ws, out);
  k_final<<<NPTS / 256, 256, 0, stream>>>(X, ws, out);
}

// Round 3
// 163.098 us; speedup vs baseline: 9.3052x; 1.4269x over previous
//
#include <hip/hip_runtime.h>
#include <cfloat>
#include <cmath>

#define NPTS 131072
#define NC   512

// ws float-index layout:
//  PM4  [0, 2048)    : folded per-component float4 (2*mu/2s2, w - |mu|^2/2s2)
//  PQ4  [2048, 4096) : per-component float4 (mu_new[3], A_c)
//  S    [4096, 4608) : sum gamma per component
//  T    [4608, 6144) : sum gamma*x per component [c][3]
//  MISC [6144, 6152) : [0]=sum|x|^2, [1]=inv2s2_new, [2]=d*log(sigma_new)
// z_n staged in d_out[3n] (k_estep writes, k_final reads then overwrites).
#define PM4_OFF  0
#define PQ4_OFF  2048
#define S_OFF    4096
#define T_OFF    4608
#define MISC_OFF 6144

__device__ __forceinline__ float waveSum(float v) {
#pragma unroll
  for (int off = 32; off > 0; off >>= 1) v += __shfl_down(v, off, 64);
  return v;
}
__device__ __forceinline__ float waveMax(float v) {
#pragma unroll
  for (int off = 32; off > 0; off >>= 1) v = fmaxf(v, __shfl_down(v, off, 64));
  return v;
}

// ---------------------------------------------------------------------------
// Prep: fold sigma/mu/w into packed pm; zero accumulators.
// ---------------------------------------------------------------------------
__global__ __launch_bounds__(512) void k_prep(
    const float* __restrict__ mu, const float* __restrict__ w,
    const float* __restrict__ sigma, float4* __restrict__ pm,
    float* __restrict__ Sacc, float* __restrict__ Tacc,
    float* __restrict__ misc) {
  const int t = threadIdx.x;  // component id
  const float sg = sigma[0];
  const float inv2s2 = 1.0f / (2.0f * sg * sg);
  const float m0 = mu[3 * t], m1 = mu[3 * t + 1], m2 = mu[3 * t + 2];
  pm[t] = make_float4(2.0f * inv2s2 * m0, 2.0f * inv2s2 * m1, 2.0f * inv2s2 * m2,
                      w[t] - (m0 * m0 + m1 * m1 + m2 * m2) * inv2s2);
  Sacc[t] = 0.f;
  Tacc[3 * t] = 0.f;
  Tacc[3 * t + 1] = 0.f;
  Tacc[3 * t + 2] = 0.f;
  if (t < 8) misc[t] = 0.f;
}

// ---------------------------------------------------------------------------
// E-step: block = 1024 thr = 256 points x 4 component-chunks (128 comps).
// Phase A: per-chunk partial (max, sumexp) -> LDS combine -> z_n.
// Phase C: transposed S,T accumulation (1 comp/thread, half the points),
//          halves combined in LDS, one global atomicAdd set per comp/block.
// ---------------------------------------------------------------------------
__global__ __launch_bounds__(1024, 4) void k_estep(
    const float* __restrict__ X, const float4* __restrict__ pm,
    float* __restrict__ Sacc, float* __restrict__ Tacc,
    float* __restrict__ misc, float* __restrict__ out) {
  __shared__ float4 s_pt[256];       // (x0,x1,x2,z)
  __shared__ float2 s_ms[4][256];    // per-chunk (max, sumexp)
  __shared__ float4 s_half[512];     // half-1 partial (Tx,Ty,Tz,S)
  __shared__ float  s_red[16];

  const int t = threadIdx.x;
  const int p = t & 255;
  const int ch = __builtin_amdgcn_readfirstlane(t >> 8);  // wave-uniform
  const int n = blockIdx.x * 256 + p;
  const float x0 = X[3 * n], x1 = X[3 * n + 1], x2 = X[3 * n + 2];

  // --- phase A: partial max / sumexp over this chunk's 128 comps ---
  const float4* __restrict__ pmc = pm + ch * 128;
  float ma = -FLT_MAX, mb = -FLT_MAX;
#pragma unroll 8
  for (int i = 0; i < 128; i += 2) {
    float4 a = pmc[i], b = pmc[i + 1];
    ma = fmaxf(ma, fmaf(a.x, x0, fmaf(a.y, x1, fmaf(a.z, x2, a.w))));
    mb = fmaxf(mb, fmaf(b.x, x0, fmaf(b.y, x1, fmaf(b.z, x2, b.w))));
  }
  const float m = fmaxf(ma, mb);
  float sa = 0.f, sb = 0.f;
#pragma unroll 8
  for (int i = 0; i < 128; i += 2) {
    float4 a = pmc[i], b = pmc[i + 1];
    sa += __expf(fmaf(a.x, x0, fmaf(a.y, x1, fmaf(a.z, x2, a.w))) - m);
    sb += __expf(fmaf(b.x, x0, fmaf(b.y, x1, fmaf(b.z, x2, b.w))) - m);
  }
  s_ms[ch][p] = make_float2(m, sa + sb);
  __syncthreads();

  if (ch == 0) {  // combine 4 chunk partials -> z
    float2 q0 = s_ms[0][p], q1 = s_ms[1][p], q2 = s_ms[2][p], q3 = s_ms[3][p];
    float M = fmaxf(fmaxf(q0.x, q1.x), fmaxf(q2.x, q3.x));
    float SS = q0.y * __expf(q0.x - M) + q1.y * __expf(q1.x - M) +
               q2.y * __expf(q2.x - M) + q3.y * __expf(q3.x - M);
    float z = M + __logf(SS);
    s_pt[p] = make_float4(x0, x1, x2, z);
    out[3 * n] = z;  // staged for k_final
  }
  __syncthreads();

  // --- phase C: thread owns comp (t&511) for half of the 256 points ---
  const int comp = t & 511;
  const int half = __builtin_amdgcn_readfirstlane(t >> 9);
  const float4 pc = pm[comp];
  const float4* sp = s_pt + half * 128;
  float Sg = 0.f, Tx = 0.f, Ty = 0.f, Tz = 0.f;
#pragma unroll 4
  for (int i = 0; i < 128; ++i) {
    float4 pt = sp[i];  // broadcast read
    float l = fmaf(pc.x, pt.x, fmaf(pc.y, pt.y, fmaf(pc.z, pt.z, pc.w)));
    float g = __expf(l - pt.w);
    Sg += g;
    Tx = fmaf(g, pt.x, Tx);
    Ty = fmaf(g, pt.y, Ty);
    Tz = fmaf(g, pt.z, Tz);
  }
  if (half) s_half[comp] = make_float4(Tx, Ty, Tz, Sg);
  __syncthreads();
  if (!half) {
    float4 o = s_half[comp];
    atomicAdd(&Sacc[comp], Sg + o.w);
    atomicAdd(&Tacc[3 * comp], Tx + o.x);
    atomicAdd(&Tacc[3 * comp + 1], Ty + o.y);
    atomicAdd(&Tacc[3 * comp + 2], Tz + o.z);
  }

  // --- sum |x|^2 (each point counted once: ch==0 threads) ---
  float q = (ch == 0) ? (x0 * x0 + x1 * x1 + x2 * x2) : 0.f;
  float r = waveSum(q);
  if ((t & 63) == 0) s_red[t >> 6] = r;
  __syncthreads();
  if (t == 0) {
    float v = 0.f;
#pragma unroll
    for (int i = 0; i < 16; ++i) v += s_red[i];
    atomicAdd(&misc[0], v);
  }
}

// ---------------------------------------------------------------------------
// M-step: one block, 512 threads (one per component).
// gd = sum|x|^2 + sum_c (S_c|mu_c|^2 - 2 mu_c . T_c);  logpi = h - lse(h).
// ---------------------------------------------------------------------------
__global__ __launch_bounds__(512) void k_mstep(
    const float* __restrict__ mu, const float* __restrict__ Sacc,
    const float* __restrict__ Tacc, float4* __restrict__ pq,
    float* __restrict__ misc, float* __restrict__ out) {
  __shared__ float s_red[8];
  __shared__ float s_red2[8];
  __shared__ float s_bc[4];
  const int t = threadIdx.x;

  const float S = Sacc[t];
  const float Sc = fmaxf(S, 1e-30f);
  const float h = __logf(Sc);
  const float T0 = Tacc[3 * t], T1 = Tacc[3 * t + 1], T2 = Tacc[3 * t + 2];
  const float m0 = T0 / Sc, m1 = T1 / Sc, m2 = T2 / Sc;

  const float o0 = mu[3 * t], o1 = mu[3 * t + 1], o2 = mu[3 * t + 2];
  const float gdp = S * (o0 * o0 + o1 * o1 + o2 * o2)
                    - 2.0f * (o0 * T0 + o1 * T1 + o2 * T2);

  float hm = waveMax(h);
  if ((t & 63) == 0) s_red[t >> 6] = hm;
  __syncthreads();
  if (t == 0) {
    float v = s_red[0];
    for (int i = 1; i < 8; ++i) v = fmaxf(v, s_red[i]);
    s_bc[0] = v;
  }
  __syncthreads();
  const float hM = s_bc[0];

  float es = waveSum(__expf(h - hM));
  float gs = waveSum(gdp);
  if ((t & 63) == 0) { s_red[t >> 6] = es; s_red2[t >> 6] = gs; }
  __syncthreads();
  if (t == 0) {
    float esum = 0.f, gsum = 0.f;
    for (int i = 0; i < 8; ++i) { esum += s_red[i]; gsum += s_red2[i]; }
    s_bc[1] = hM + __logf(esum);                           // lse(h)
    const float gd = fmaxf(misc[0] + gsum, 1e-20f);
    const float sn2 = gd * (1.0f / (3.0f * (float)NPTS));  // sigma_new^2
    s_bc[2] = 1.0f / (2.0f * sn2);
    s_bc[3] = 1.5f * __logf(sn2);                          // d*log(sigma_new)
  }
  __syncthreads();

  const float logpi = h - s_bc[1];
  const float A = (m0 * m0 + m1 * m1 + m2 * m2) * s_bc[2] - logpi;
  pq[t] = make_float4(m0, m1, m2, A);
  if (t == 0) {
    misc[1] = s_bc[2];
    misc[2] = s_bc[3];
    out[NPTS * 3] = 0.f;  // Cfe accumulator
  }
}

// ---------------------------------------------------------------------------
// Final: block = 1024 thr = 256 points x 4 chunks. Partial Y/acc/sumg per
// chunk, LDS combine, then Cfe (nonlinear |Y|^2 handled after combine).
// ---------------------------------------------------------------------------
__global__ __launch_bounds__(1024, 4) void k_final(
    const float* __restrict__ X, const float4* __restrict__ pm,
    const float4* __restrict__ pq, const float* __restrict__ misc,
    float* __restrict__ out) {
  __shared__ float4 s_y[4][256];  // (y0,y1,y2,acc)
  __shared__ float  s_g[4][256];  // sumg
  __shared__ float  s_red[16];

  const int t = threadIdx.x;
  const int p = t & 255;
  const int ch = __builtin_amdgcn_readfirstlane(t >> 8);
  const int n = blockIdx.x * 256 + p;
  const float x0 = X[3 * n], x1 = X[3 * n + 1], x2 = X[3 * n + 2];
  const float z = out[3 * n];  // staged by k_estep (read precedes barrier+write)
  const float inv2s2n = misc[1], dlogsig = misc[2];

  const float4* __restrict__ pmc = pm + ch * 128;
  const float4* __restrict__ pqc = pq + ch * 128;
  float y0 = 0.f, y1 = 0.f, y2 = 0.f, acc = 0.f, sg = 0.f;
#pragma unroll 4
  for (int i = 0; i < 128; ++i) {
    float4 pp = pmc[i];
    float4 qq = pqc[i];
    float l = fmaf(pp.x, x0, fmaf(pp.y, x1, fmaf(pp.z, x2, pp.w))) - z;  // lgamma
    float g = __expf(l);
    sg += g;
    y0 = fmaf(g, qq.x, y0);
    y1 = fmaf(g, qq.y, y1);
    y2 = fmaf(g, qq.z, y2);
    acc = fmaf(g, qq.w + l, acc);
  }
  s_y[ch][p] = make_float4(y0, y1, y2, acc);
  s_g[ch][p] = sg;
  __syncthreads();

  float cfe = 0.f;
  if (ch == 0) {
    float4 a0 = s_y[0][p], a1 = s_y[1][p], a2 = s_y[2][p], a3 = s_y[3][p];
    float Y0 = a0.x + a1.x + a2.x + a3.x;
    float Y1 = a0.y + a1.y + a2.y + a3.y;
    float Y2 = a0.z + a1.z + a2.z + a3.z;
    float A  = a0.w + a1.w + a2.w + a3.w;
    float G  = s_g[0][p] + s_g[1][p] + s_g[2][p] + s_g[3][p];
    float yn2 = Y0 * Y0 + Y1 * Y1 + Y2 * Y2;
    cfe = A + G * (dlogsig - yn2 * inv2s2n);
    out[3 * n] = Y0;
    out[3 * n + 1] = Y1;
    out[3 * n + 2] = Y2;
  }
  float r = waveSum(cfe);
  if ((t & 63) == 0) s_red[t >> 6] = r;
  __syncthreads();
  if (t == 0) {
    float v = 0.f;
#pragma unroll
    for (int i = 0; i < 16; ++i) v += s_red[i];
    atomicAdd(&out[NPTS * 3], v);
  }
}

extern "C" void kernel_launch(void* const* d_in, const int* in_sizes, int n_in,
                              void* d_out, int out_size, void* d_ws, size_t ws_size,
                              hipStream_t stream) {
  const float* X = (const float*)d_in[0];
  const float* mu = (const float*)d_in[1];
  const float* w = (const float*)d_in[2];
  const float* sigma = (const float*)d_in[3];
  float* out = (float*)d_out;
  float* ws = (float*)d_ws;

  float4* pm = (float4*)(ws + PM4_OFF);
  float4* pq = (float4*)(ws + PQ4_OFF);
  float* Sacc = ws + S_OFF;
  float* Tacc = ws + T_OFF;
  float* misc = ws + MISC_OFF;

  k_prep<<<1, 512, 0, stream>>>(mu, w, sigma, pm, Sacc, Tacc, misc);
  k_estep<<<NPTS / 256, 1024, 0, stream>>>(X, pm, Sacc, Tacc, misc, out);
  k_mstep<<<1, 512, 0, stream>>>(mu, Sacc, Tacc, pq, misc, out);
  k_final<<<NPTS / 256, 1024, 0, stream>>>(X, pm, pq, misc, out);
}

// Round 4
// 145.951 us; speedup vs baseline: 10.3984x; 1.1175x over previous
//
#include <hip/hip_runtime.h>
#include <cfloat>
#include <cmath>

#define NPTS 131072
#define NC   512
#define NREP 4

// ws float-index layout:
//  PM4  [0, 2048)      : per-component float4 (2*mu/2s2, w - |mu|^2/2s2)
//  PQ4  [2048, 4096)   : per-component float4 (mu_new[3], A_c)
//  ST4  [4096, 12288)  : NREP replicas x 512 comps x float4 (Tx,Ty,Tz,S)
//  MISC [12288, 12296) : [0]=sum|x|^2, [1]=inv2s2_new, [3]=sum(gamma*lgamma)
// z_n staged in d_out[3n] (k_estep writes, k_final reads then overwrites).
#define PM4_OFF  0
#define PQ4_OFF  2048
#define ST4_OFF  4096
#define MISC_OFF 12288

__device__ __forceinline__ float waveSum(float v) {
#pragma unroll
  for (int off = 32; off > 0; off >>= 1) v += __shfl_down(v, off, 64);
  return v;
}
__device__ __forceinline__ float waveMax(float v) {
#pragma unroll
  for (int off = 32; off > 0; off >>= 1) v = fmaxf(v, __shfl_down(v, off, 64));
  return v;
}

// ---------------------------------------------------------------------------
// Prep: fold sigma/mu/w into packed pm; zero ST replicas + misc.
// ---------------------------------------------------------------------------
__global__ __launch_bounds__(512) void k_prep(
    const float* __restrict__ mu, const float* __restrict__ w,
    const float* __restrict__ sigma, float4* __restrict__ pm,
    float* __restrict__ ST, float* __restrict__ misc) {
  const int t = threadIdx.x;  // component id
  const float sg = sigma[0];
  const float inv2s2 = 1.0f / (2.0f * sg * sg);
  const float m0 = mu[3 * t], m1 = mu[3 * t + 1], m2 = mu[3 * t + 2];
  pm[t] = make_float4(2.0f * inv2s2 * m0, 2.0f * inv2s2 * m1, 2.0f * inv2s2 * m2,
                      w[t] - (m0 * m0 + m1 * m1 + m2 * m2) * inv2s2);
#pragma unroll
  for (int r = 0; r < NREP * 4; ++r) ST[r * 512 + t] = 0.f;
  if (t < 8) misc[t] = 0.f;
}

// ---------------------------------------------------------------------------
// E-step: block = 512 thr = 128 points x 4 comp-chunks (128 comps each).
// Phase A: per-chunk (max, sumexp) -> LDS combine -> z_n.
// Phase C: thread owns ONE comp over the 128 points (LDS broadcast reads);
//          also accumulates sum(gamma*lgamma). Atomics to replica blockIdx&3.
// ---------------------------------------------------------------------------
__global__ __launch_bounds__(512, 8) void k_estep(
    const float* __restrict__ X, const float4* __restrict__ pm,
    float* __restrict__ ST, float* __restrict__ misc,
    float* __restrict__ out) {
  __shared__ float4 s_pt[128];     // (x0,x1,x2,z)
  __shared__ float2 s_ms[4][128];  // per-chunk (max, sumexp)
  __shared__ float  s_red[8];
  __shared__ float  s_red2[8];

  const int t = threadIdx.x;
  const int p = t & 127;
  const int ch = __builtin_amdgcn_readfirstlane(t >> 7);  // wave-uniform
  const int n = blockIdx.x * 128 + p;
  const float x0 = X[3 * n], x1 = X[3 * n + 1], x2 = X[3 * n + 2];

  // --- phase A: partial max / sumexp over this chunk's 128 comps ---
  const float4* __restrict__ pmc = pm + ch * 128;
  float ma = -FLT_MAX, mb = -FLT_MAX, mc = -FLT_MAX, md = -FLT_MAX;
#pragma unroll 4
  for (int i = 0; i < 128; i += 4) {
    float4 a = pmc[i], b = pmc[i + 1], c = pmc[i + 2], d = pmc[i + 3];
    ma = fmaxf(ma, fmaf(a.x, x0, fmaf(a.y, x1, fmaf(a.z, x2, a.w))));
    mb = fmaxf(mb, fmaf(b.x, x0, fmaf(b.y, x1, fmaf(b.z, x2, b.w))));
    mc = fmaxf(mc, fmaf(c.x, x0, fmaf(c.y, x1, fmaf(c.z, x2, c.w))));
    md = fmaxf(md, fmaf(d.x, x0, fmaf(d.y, x1, fmaf(d.z, x2, d.w))));
  }
  const float m = fmaxf(fmaxf(ma, mb), fmaxf(mc, md));
  float sa = 0.f, sb = 0.f, sc = 0.f, sd = 0.f;
#pragma unroll 4
  for (int i = 0; i < 128; i += 4) {
    float4 a = pmc[i], b = pmc[i + 1], c = pmc[i + 2], d = pmc[i + 3];
    sa += __expf(fmaf(a.x, x0, fmaf(a.y, x1, fmaf(a.z, x2, a.w))) - m);
    sb += __expf(fmaf(b.x, x0, fmaf(b.y, x1, fmaf(b.z, x2, b.w))) - m);
    sc += __expf(fmaf(c.x, x0, fmaf(c.y, x1, fmaf(c.z, x2, c.w))) - m);
    sd += __expf(fmaf(d.x, x0, fmaf(d.y, x1, fmaf(d.z, x2, d.w))) - m);
  }
  s_ms[ch][p] = make_float2(m, (sa + sb) + (sc + sd));
  __syncthreads();

  if (t < 128) {  // thread t owns point p == t here
    float2 q0 = s_ms[0][t], q1 = s_ms[1][t], q2 = s_ms[2][t], q3 = s_ms[3][t];
    float M = fmaxf(fmaxf(q0.x, q1.x), fmaxf(q2.x, q3.x));
    float SS = q0.y * __expf(q0.x - M) + q1.y * __expf(q1.x - M) +
               q2.y * __expf(q2.x - M) + q3.y * __expf(q3.x - M);
    float z = M + __logf(SS);
    s_pt[t] = make_float4(x0, x1, x2, z);
    out[3 * n] = z;  // staged for k_final
  }
  __syncthreads();

  // --- phase C: thread t owns comp t across the block's 128 points ---
  const float4 pc = pm[t];  // coalesced per-lane load
  float Sg = 0.f, Tx = 0.f, Ty = 0.f, Tz = 0.f, La = 0.f;
#pragma unroll 4
  for (int i = 0; i < 128; ++i) {
    float4 pt = s_pt[i];  // broadcast read
    float l = fmaf(pc.x, pt.x, fmaf(pc.y, pt.y, fmaf(pc.z, pt.z, pc.w)));
    float d = l - pt.w;   // lgamma
    float g = __expf(d);
    Sg += g;
    Tx = fmaf(g, pt.x, Tx);
    Ty = fmaf(g, pt.y, Ty);
    Tz = fmaf(g, pt.z, Tz);
    La = fmaf(g, d, La);  // sum gamma * lgamma
  }
  float* st = ST + (((blockIdx.x & (NREP - 1)) * 512 + t) << 2);
  atomicAdd(st + 0, Tx);
  atomicAdd(st + 1, Ty);
  atomicAdd(st + 2, Tz);
  atomicAdd(st + 3, Sg);

  // --- block reduce: sum|x|^2 (points counted once via ch==0) and La ---
  float xx = (t < 128) ? (x0 * x0 + x1 * x1 + x2 * x2) : 0.f;
  float rx = waveSum(xx);
  float rl = waveSum(La);
  if ((t & 63) == 0) { s_red[t >> 6] = rx; s_red2[t >> 6] = rl; }
  __syncthreads();
  if (t == 0) {
    float vx = 0.f, vl = 0.f;
#pragma unroll
    for (int i = 0; i < 8; ++i) { vx += s_red[i]; vl += s_red2[i]; }
    atomicAdd(&misc[0], vx);
    atomicAdd(&misc[3], vl);
  }
}

// ---------------------------------------------------------------------------
// M-step: one block, 512 threads (one per component). Sums ST replicas.
// gd = sum|x|^2 + sum_c (S_c|mu_c|^2 - 2 mu_c.T_c);  logpi = h - lse(h).
// Also seeds the Cfe accumulator: sum_c S_c A_c + sum(gamma lgamma) + N dlogs.
// ---------------------------------------------------------------------------
__global__ __launch_bounds__(512) void k_mstep(
    const float* __restrict__ mu, const float4* __restrict__ ST4,
    float4* __restrict__ pq, float* __restrict__ misc,
    float* __restrict__ out) {
  __shared__ float s_red[8];
  __shared__ float s_red2[8];
  __shared__ float s_bc[4];
  const int t = threadIdx.x;

  float Tx = 0.f, Ty = 0.f, Tz = 0.f, S = 0.f;
#pragma unroll
  for (int r = 0; r < NREP; ++r) {
    float4 v = ST4[r * 512 + t];
    Tx += v.x; Ty += v.y; Tz += v.z; S += v.w;
  }
  const float Sc = fmaxf(S, 1e-30f);
  const float h = __logf(Sc);
  const float m0 = Tx / Sc, m1 = Ty / Sc, m2 = Tz / Sc;

  const float o0 = mu[3 * t], o1 = mu[3 * t + 1], o2 = mu[3 * t + 2];
  const float gdp = S * (o0 * o0 + o1 * o1 + o2 * o2)
                    - 2.0f * (o0 * Tx + o1 * Ty + o2 * Tz);

  float hm = waveMax(h);
  if ((t & 63) == 0) s_red[t >> 6] = hm;
  __syncthreads();
  if (t == 0) {
    float v = s_red[0];
    for (int i = 1; i < 8; ++i) v = fmaxf(v, s_red[i]);
    s_bc[0] = v;
  }
  __syncthreads();
  const float hM = s_bc[0];

  float es = waveSum(__expf(h - hM));
  float gs = waveSum(gdp);
  if ((t & 63) == 0) { s_red[t >> 6] = es; s_red2[t >> 6] = gs; }
  __syncthreads();
  if (t == 0) {
    float esum = 0.f, gsum = 0.f;
    for (int i = 0; i < 8; ++i) { esum += s_red[i]; gsum += s_red2[i]; }
    s_bc[1] = hM + __logf(esum);                           // lse(h)
    const float gd = fmaxf(misc[0] + gsum, 1e-20f);
    const float sn2 = gd * (1.0f / (3.0f * (float)NPTS));  // sigma_new^2
    s_bc[2] = 1.0f / (2.0f * sn2);                         // inv2s2_new
    s_bc[3] = 1.5f * __logf(sn2);                          // d*log(sigma_new)
  }
  __syncthreads();

  const float inv2s2n = s_bc[2];
  const float logpi = h - s_bc[1];
  const float A = (m0 * m0 + m1 * m1 + m2 * m2) * inv2s2n - logpi;
  pq[t] = make_float4(m0, m1, m2, A);

  // Cfe seed: sum_c S_c * A_c  (true S: empty comps contribute 0)
  float ca = waveSum(S * A);
  if ((t & 63) == 0) s_red[t >> 6] = ca;
  __syncthreads();
  if (t == 0) {
    float v = 0.f;
    for (int i = 0; i < 8; ++i) v += s_red[i];
    out[NPTS * 3] = v + misc[3] + (float)NPTS * s_bc[3];
    misc[1] = inv2s2n;
  }
}

// ---------------------------------------------------------------------------
// Final: block = 512 thr = 128 points x 4 chunks. Y = gamma @ mu_new only;
// Cfe contribution is -|Y|^2 * inv2s2n per point (rest seeded in k_mstep).
// ---------------------------------------------------------------------------
__global__ __launch_bounds__(512, 8) void k_final(
    const float* __restrict__ X, const float4* __restrict__ pm,
    const float4* __restrict__ pq, const float* __restrict__ misc,
    float* __restrict__ out) {
  __shared__ float4 s_y[4][128];
  __shared__ float  s_red[8];

  const int t = threadIdx.x;
  const int p = t & 127;
  const int ch = __builtin_amdgcn_readfirstlane(t >> 7);
  const int n = blockIdx.x * 128 + p;
  const float x0 = X[3 * n], x1 = X[3 * n + 1], x2 = X[3 * n + 2];
  const float z = out[3 * n];  // staged by k_estep; overwritten after barrier
  const float inv2s2n = misc[1];

  const float4* __restrict__ pmc = pm + ch * 128;
  const float4* __restrict__ pqc = pq + ch * 128;
  float y0 = 0.f, y1 = 0.f, y2 = 0.f;
#pragma unroll 4
  for (int i = 0; i < 128; ++i) {
    float4 pp = pmc[i];
    float4 qq = pqc[i];
    float l = fmaf(pp.x, x0, fmaf(pp.y, x1, fmaf(pp.z, x2, pp.w))) - z;
    float g = __expf(l);
    y0 = fmaf(g, qq.x, y0);
    y1 = fmaf(g, qq.y, y1);
    y2 = fmaf(g, qq.z, y2);
  }
  s_y[ch][p] = make_float4(y0, y1, y2, 0.f);
  __syncthreads();

  float cfe = 0.f;
  if (t < 128) {
    float4 a0 = s_y[0][t], a1 = s_y[1][t], a2 = s_y[2][t], a3 = s_y[3][t];
    float Y0 = (a0.x + a1.x) + (a2.x + a3.x);
    float Y1 = (a0.y + a1.y) + (a2.y + a3.y);
    float Y2 = (a0.z + a1.z) + (a2.z + a3.z);
    cfe = -(Y0 * Y0 + Y1 * Y1 + Y2 * Y2) * inv2s2n;
    out[3 * n] = Y0;
    out[3 * n + 1] = Y1;
    out[3 * n + 2] = Y2;
  }
  float r = waveSum(cfe);
  if ((t & 63) == 0) s_red[t >> 6] = r;
  __syncthreads();
  if (t == 0) {
    float v = 0.f;
#pragma unroll
    for (int i = 0; i < 8; ++i) v += s_red[i];
    atomicAdd(&out[NPTS * 3], v);
  }
}

extern "C" void kernel_launch(void* const* d_in, const int* in_sizes, int n_in,
                              void* d_out, int out_size, void* d_ws, size_t ws_size,
                              hipStream_t stream) {
  const float* X = (const float*)d_in[0];
  const float* mu = (const float*)d_in[1];
  const float* w = (const float*)d_in[2];
  const float* sigma = (const float*)d_in[3];
  float* out = (float*)d_out;
  float* ws = (float*)d_ws;

  float4* pm = (float4*)(ws + PM4_OFF);
  float4* pq = (float4*)(ws + PQ4_OFF);
  float* ST = ws + ST4_OFF;
  float* misc = ws + MISC_OFF;

  k_prep<<<1, 512, 0, stream>>>(mu, w, sigma, pm, ST, misc);
  k_estep<<<NPTS / 128, 512, 0, stream>>>(X, pm, ST, misc, out);
  k_mstep<<<1, 512, 0, stream>>>(mu, (const float4*)ST, pq, misc, out);
  k_final<<<NPTS / 128, 512, 0, stream>>>(X, pm, pq, misc, out);
}